// Round 2
// baseline (350.956 us; speedup 1.0000x reference)
//
#include <hip/hip_runtime.h>
#include <math.h>

#define BB  32
#define CCH 1024
#define HH  64
#define WW  64
#define JJ  128
#define NP  4
#define HID 128
#define G   8      // batches per L3 group
#define NG  (BB/G) // 4 groups

typedef float f4 __attribute__((ext_vector_type(4)));
typedef float f2 __attribute__((ext_vector_type(2)));

__device__ __forceinline__ float bilin(const float* pl, float ix, float iy) {
  float x0f = floorf(ix), y0f = floorf(iy);
  float wx1 = ix - x0f, wx0 = 1.0f - wx1;
  float wy1 = iy - y0f, wy0 = 1.0f - wy1;
  int x0 = (int)x0f, y0 = (int)y0f;
  int x1 = x0 + 1, y1 = y0 + 1;
  float v = 0.0f;
  if (y0 >= 0 && y0 < HH) {
    if (x0 >= 0 && x0 < WW) v += pl[y0*WW + x0] * (wx0*wy0);
    if (x1 >= 0 && x1 < WW) v += pl[y0*WW + x1] * (wx1*wy0);
  }
  if (y1 >= 0 && y1 < HH) {
    if (x0 >= 0 && x0 < WW) v += pl[y1*WW + x0] * (wx0*wy1);
    if (x1 >= 0 && x1 < WW) v += pl[y1*WW + x1] * (wx1*wy1);
  }
  return v;
}

// Transpose W1 of both MLPs: w[o][c] (128x1024) -> wt[m][c][o] (1024x128)
__global__ __launch_bounds__(256) void k_wtr(const float* __restrict__ w_off1,
                                             const float* __restrict__ w_att1,
                                             float* __restrict__ wt) {
  int c0 = blockIdx.x * 32, o0 = blockIdx.y * 32, m = blockIdx.z;
  const float* src = m ? w_att1 : w_off1;
  float* dst = wt + (size_t)m * (CCH * HID);
  __shared__ float tl[32][33];
  int tx = threadIdx.x & 31, ty = threadIdx.x >> 5;
  #pragma unroll
  for (int r = 0; r < 4; ++r) {
    int o = o0 + ty + r*8;
    tl[ty + r*8][tx] = src[(size_t)o*CCH + c0 + tx];
  }
  __syncthreads();
  #pragma unroll
  for (int r = 0; r < 4; ++r) {
    int c = c0 + ty + r*8;
    dst[(size_t)c*HID + o0 + tx] = tl[tx][ty + r*8];
  }
}

// seed[b][c][j] for one group of G batches starting at b0
__global__ __launch_bounds__(256) void k_seed(const float* __restrict__ feat,
                                              const float* __restrict__ kp,
                                              float* __restrict__ sf, int b0) {
  int c = blockIdx.x, b = b0 + blockIdx.y;
  __shared__ __align__(16) float pl[HH*WW];
  const f4* p4 = (const f4*)(feat + ((size_t)(b*CCH + c)) * (size_t)(HH*WW));
  f4* s4 = (f4*)pl;
  #pragma unroll
  for (int r = 0; r < 4; ++r) s4[threadIdx.x + r*256] = p4[threadIdx.x + r*256];
  __syncthreads();
  int j = threadIdx.x;
  if (j < JJ) {
    float gx = kp[((size_t)b*JJ + j)*2 + 0];
    float gy = kp[((size_t)b*JJ + j)*2 + 1];
    float ix = (gx + 1.0f) * 0.5f * (float)(WW - 1);
    float iy = (gy + 1.0f) * 0.5f * (float)(HH - 1);
    sf[((size_t)(b*CCH + c))*JJ + j] = bilin(pl, ix, iy);
  }
}

// Partial hidden GEMM for one group. grid (8 jq, 8 ch, G bl).
// part[(ch*G+bl)*2+m][o][j] partial over c in [ch*128, ch*128+128)
__global__ __launch_bounds__(256) void k_mlp(const float* __restrict__ sf,
                                             const float* __restrict__ wt,
                                             float* __restrict__ part, int b0) {
  int jq = blockIdx.x, ch = blockIdx.y, bl = blockIdx.z;
  int b = b0 + bl;
  int j0 = jq * 16;
  __shared__ __align__(16) float sW[2][64][HID];   // 64 KB
  __shared__ __align__(16) float sS[64][16];       // 4 KB
  int t = threadIdx.x;
  int ocol = t & 31, jrow = t >> 5;
  int o0 = ocol * 4, jl0 = jrow * 2;
  f4 a00 = 0.0f, a01 = 0.0f, a10 = 0.0f, a11 = 0.0f;

  for (int ct = 0; ct < 2; ++ct) {
    int c0 = ch * 128 + ct * 64;
    // stage S tile: 64c x 16j = 256 f4
    {
      int cc = t >> 2, q = t & 3;
      *(f4*)&sS[cc][q*4] = *(const f4*)&sf[((size_t)(b*CCH + c0 + cc))*JJ + j0 + q*4];
    }
    // stage W tiles: 2 x 64c x 128o = 4096 f4
    #pragma unroll
    for (int r = 0; r < 16; ++r) {
      int idx = r * 256 + t;
      int m = idx >> 11;
      int rem = idx & 2047;
      int cc = rem >> 5, oq = rem & 31;
      *(f4*)&sW[m][cc][oq*4] =
          *(const f4*)&wt[(size_t)m*(CCH*HID) + (size_t)(c0 + cc)*HID + oq*4];
    }
    __syncthreads();
    #pragma unroll 8
    for (int cc = 0; cc < 64; ++cc) {
      f4 w0 = *(const f4*)&sW[0][cc][o0];
      f4 w1 = *(const f4*)&sW[1][cc][o0];
      float s0 = sS[cc][jl0], s1 = sS[cc][jl0 + 1];
      a00 += w0 * s0; a01 += w0 * s1;
      a10 += w1 * s0; a11 += w1 * s1;
    }
    __syncthreads();
  }
  #pragma unroll
  for (int oi = 0; oi < 4; ++oi) {
    size_t base0 = ((size_t)(ch*G + bl)*2 + 0)*16384 + (size_t)(o0+oi)*JJ + j0 + jl0;
    size_t base1 = ((size_t)(ch*G + bl)*2 + 1)*16384 + (size_t)(o0+oi)*JJ + j0 + jl0;
    f2 v0; v0[0] = a00[oi]; v0[1] = a01[oi];
    f2 v1; v1[0] = a10[oi]; v1[1] = a11[oi];
    *(f2*)&part[base0] = v0;
    *(f2*)&part[base1] = v1;
  }
}

// Reduce partials + bias + relu, layer2, softmax, grid coords. grid (4 jq, G bl)
__global__ __launch_bounds__(256) void k_head(const float* __restrict__ part,
                                              const float* __restrict__ kp,
                                              const float* __restrict__ b_off1,
                                              const float* __restrict__ w_off2,
                                              const float* __restrict__ b_off2,
                                              const float* __restrict__ b_att1,
                                              const float* __restrict__ w_att2,
                                              const float* __restrict__ b_att2,
                                              float* __restrict__ grids,
                                              float* __restrict__ attw, int b0) {
  int jq = blockIdx.x, bl = blockIdx.y;
  int b = b0 + bl;
  int j0 = jq * 32;
  __shared__ float sH[2][HID][33];
  __shared__ float sO[32][13];
  for (int idx = threadIdx.x; idx < 2*HID*32; idx += 256) {
    int m = idx >> 12;
    int rem = idx & 4095;
    int o = rem >> 5, jl = rem & 31;
    float v = 0.0f;
    #pragma unroll
    for (int ch = 0; ch < 8; ++ch)
      v += part[((size_t)(ch*G + bl)*2 + m)*16384 + (size_t)o*JJ + j0 + jl];
    v += (m ? b_att1 : b_off1)[o];
    sH[m][o][jl] = fmaxf(v, 0.0f);
  }
  __syncthreads();
  for (int idx = threadIdx.x; idx < 12*32; idx += 256) {
    int jl = idx / 12, q = idx % 12;
    int m = (q < 8) ? 0 : 1;
    int p = m ? (q - 8) : q;
    const float* w2 = m ? w_att2 : w_off2;
    float sum = (m ? b_att2 : b_off2)[p];
    for (int o = 0; o < HID; ++o) sum += w2[p*HID + o] * sH[m][o][jl];
    sO[jl][q] = sum;
  }
  __syncthreads();
  if (threadIdx.x < 32) {
    int jl = threadIdx.x, j = j0 + jl;
    float gx = kp[((size_t)b*JJ + j)*2 + 0];
    float gy = kp[((size_t)b*JJ + j)*2 + 1];
    const float sc = 2.0f / 63.0f;
    float a[NP];
    #pragma unroll
    for (int n = 0; n < NP; ++n) {
      grids[(((size_t)b*JJ + j)*NP + n)*2 + 0] = gx + sO[jl][2*n + 0]*sc;
      grids[(((size_t)b*JJ + j)*NP + n)*2 + 1] = gy + sO[jl][2*n + 1]*sc;
      a[n] = sO[jl][8 + n];
    }
    float mx = fmaxf(fmaxf(a[0], a[1]), fmaxf(a[2], a[3]));
    float e[NP], s = 0.0f;
    #pragma unroll
    for (int n = 0; n < NP; ++n) { e[n] = expf(a[n] - mx); s += e[n]; }
    float inv = 1.0f / s;
    #pragma unroll
    for (int n = 0; n < NP; ++n) attw[((size_t)b*JJ + j)*NP + n] = e[n]*inv;
  }
}

// Fused: fuse for group at b0f (feat slice L3-hot) + seed for group at b0s (HBM).
__global__ __launch_bounds__(256) void k_fs(const float* __restrict__ feat,
                                            const float* __restrict__ grids,
                                            const float* __restrict__ attw,
                                            const float* __restrict__ kp,
                                            float* __restrict__ sf,
                                            int b0f, int b0s, int doseed) {
  int c = blockIdx.x, by = blockIdx.y;
  int bf = b0f + by, bs = b0s + by;
  __shared__ __align__(16) float plF[HH*WW];
  __shared__ __align__(16) float plS[HH*WW];
  __shared__ float sG[JJ*NP*2];
  __shared__ float sA[JJ*NP];
  __shared__ float sKP[JJ*2];
  int t = threadIdx.x;
  // issue HBM loads (next-group seed plane) first, then L3-hot fuse plane
  f4 rs[4];
  const f4* p4s = (const f4*)(feat + ((size_t)(bs*CCH + c)) * (size_t)(HH*WW));
  if (doseed) {
    #pragma unroll
    for (int r = 0; r < 4; ++r) rs[r] = p4s[t + r*256];
  }
  f4 rf[4];
  const f4* p4f = (const f4*)(feat + ((size_t)(bf*CCH + c)) * (size_t)(HH*WW));
  #pragma unroll
  for (int r = 0; r < 4; ++r) rf[r] = p4f[t + r*256];
  // small tables
  ((f4*)sG)[t] = ((const f4*)(grids + (size_t)bf*JJ*NP*2))[t];
  if (t < 128) ((f4*)sA)[t] = ((const f4*)(attw + (size_t)bf*JJ*NP))[t];
  if (doseed && t < 64) ((f4*)sKP)[t] = ((const f4*)(kp + (size_t)bs*JJ*2))[t];
  f4* sF4 = (f4*)plF;
  #pragma unroll
  for (int r = 0; r < 4; ++r) sF4[t + r*256] = rf[r];
  if (doseed) {
    f4* sS4 = (f4*)plS;
    #pragma unroll
    for (int r = 0; r < 4; ++r) sS4[t + r*256] = rs[r];
  }
  __syncthreads();
  int j = t;
  if (j < JJ) {
    float acc = 0.0f;
    #pragma unroll
    for (int n = 0; n < NP; ++n) {
      float gx = sG[(j*NP + n)*2 + 0];
      float gy = sG[(j*NP + n)*2 + 1];
      float ix = (gx + 1.0f) * 0.5f * (float)(WW - 1);
      float iy = (gy + 1.0f) * 0.5f * (float)(HH - 1);
      acc += sA[j*NP + n] * bilin(plF, ix, iy);
    }
    sf[((size_t)(bf*CCH + c))*JJ + j] = acc;   // fusedT overwrites consumed seed
    if (doseed) {
      float gx = sKP[j*2 + 0], gy = sKP[j*2 + 1];
      float ix = (gx + 1.0f) * 0.5f * (float)(WW - 1);
      float iy = (gy + 1.0f) * 0.5f * (float)(HH - 1);
      sf[((size_t)(bs*CCH + c))*JJ + j] = bilin(plS, ix, iy);
    }
  }
}

// out[b][j][c] = fusedT[b][c][j]
__global__ __launch_bounds__(256) void k_tr(const float* __restrict__ fusedT,
                                            float* __restrict__ out) {
  int b = blockIdx.z;
  int c0 = blockIdx.x * 32, j0 = blockIdx.y * 32;
  __shared__ float tl[32][33];
  int tx = threadIdx.x & 31, ty = threadIdx.x >> 5;
  #pragma unroll
  for (int r = 0; r < 4; ++r) {
    int cc = ty + r*8;
    tl[cc][tx] = fusedT[((size_t)(b*CCH + c0 + cc))*JJ + j0 + tx];
  }
  __syncthreads();
  #pragma unroll
  for (int r = 0; r < 4; ++r) {
    int jj = ty + r*8;
    out[((size_t)(b*JJ + j0 + jj))*CCH + c0 + tx] = tl[tx][jj];
  }
}

extern "C" void kernel_launch(void* const* d_in, const int* in_sizes, int n_in,
                              void* d_out, int out_size, void* d_ws, size_t ws_size,
                              hipStream_t stream) {
  const float* feat   = (const float*)d_in[0];
  const float* kp     = (const float*)d_in[1];
  const float* w_off1 = (const float*)d_in[2];
  const float* b_off1 = (const float*)d_in[3];
  const float* w_off2 = (const float*)d_in[4];
  const float* b_off2 = (const float*)d_in[5];
  const float* w_att1 = (const float*)d_in[6];
  const float* b_att1 = (const float*)d_in[7];
  const float* w_att2 = (const float*)d_in[8];
  const float* b_att2 = (const float*)d_in[9];
  float* out = (float*)d_out;

  // workspace (floats):
  //   wt    : 0       .. 262144         (transposed W1, both MLPs)
  //   sf    : 262144  .. 4456448        (seed / fusedT, per-batch lifetime)
  //   part  : 4456448 .. 6553600        (8 c-chunk partials for one group)
  //   grids : 6553600 .. 6586368
  //   attw  : 6586368 .. 6602752        (~26.4 MB)
  float* ws    = (float*)d_ws;
  float* wt    = ws;
  float* sf    = ws + (size_t)262144;
  float* part  = ws + (size_t)4456448;
  float* grids = ws + (size_t)6553600;
  float* attwb = ws + (size_t)6586368;

  k_wtr <<<dim3(CCH/32, HID/32, 2), 256, 0, stream>>>(w_off1, w_att1, wt);
  k_seed<<<dim3(CCH, G), 256, 0, stream>>>(feat, kp, sf, 0);
  for (int g = 0; g < NG; ++g) {
    int b0 = g * G;
    k_mlp <<<dim3(8, 8, G), 256, 0, stream>>>(sf, wt, part, b0);
    k_head<<<dim3(4, G), 256, 0, stream>>>(part, kp, b_off1, w_off2, b_off2,
                                           b_att1, w_att2, b_att2, grids, attwb, b0);
    int doseed = (g < NG - 1) ? 1 : 0;
    k_fs  <<<dim3(CCH, G), 256, 0, stream>>>(feat, grids, attwb, kp, sf,
                                             b0, b0 + G, doseed);
  }
  k_tr  <<<dim3(CCH/32, JJ/32, BB), 256, 0, stream>>>(sf, out);
}

// Round 3
// 288.625 us; speedup vs baseline: 1.2160x; 1.2160x over previous
//
#include <hip/hip_runtime.h>
#include <math.h>

#define BB  32
#define CCH 1024
#define HH  64
#define WW  64
#define JJ  128
#define NP  4
#define HID 128

typedef float f4 __attribute__((ext_vector_type(4)));
typedef float f2 __attribute__((ext_vector_type(2)));

__device__ __forceinline__ float bilin(const float* pl, float ix, float iy) {
  float x0f = floorf(ix), y0f = floorf(iy);
  float wx1 = ix - x0f, wx0 = 1.0f - wx1;
  float wy1 = iy - y0f, wy0 = 1.0f - wy1;
  int x0 = (int)x0f, y0 = (int)y0f;
  int x1 = x0 + 1, y1 = y0 + 1;
  float v = 0.0f;
  if (y0 >= 0 && y0 < HH) {
    if (x0 >= 0 && x0 < WW) v += pl[y0*WW + x0] * (wx0*wy0);
    if (x1 >= 0 && x1 < WW) v += pl[y0*WW + x1] * (wx1*wy0);
  }
  if (y1 >= 0 && y1 < HH) {
    if (x0 >= 0 && x0 < WW) v += pl[y1*WW + x0] * (wx0*wy1);
    if (x1 >= 0 && x1 < WW) v += pl[y1*WW + x1] * (wx1*wy1);
  }
  return v;
}

// Transpose W1 of both MLPs: w[o][c] (128x1024) -> wt[m][c][o] (1024x128)
__global__ __launch_bounds__(256) void k_wtr(const float* __restrict__ w_off1,
                                             const float* __restrict__ w_att1,
                                             float* __restrict__ wt) {
  int c0 = blockIdx.x * 32, o0 = blockIdx.y * 32, m = blockIdx.z;
  const float* src = m ? w_att1 : w_off1;
  float* dst = wt + (size_t)m * (CCH * HID);
  __shared__ float tl[32][33];
  int tx = threadIdx.x & 31, ty = threadIdx.x >> 5;
  #pragma unroll
  for (int r = 0; r < 4; ++r) {
    int o = o0 + ty + r*8;
    tl[ty + r*8][tx] = src[(size_t)o*CCH + c0 + tx];
  }
  __syncthreads();
  #pragma unroll
  for (int r = 0; r < 4; ++r) {
    int c = c0 + ty + r*8;
    dst[(size_t)c*HID + o0 + tx] = tl[tx][ty + r*8];
  }
}

// seed[b][c][j] = bilinear(features[b,c,:,:], keypoint[b,j])
__global__ __launch_bounds__(256) void k_seed(const float* __restrict__ feat,
                                              const float* __restrict__ kp,
                                              float* __restrict__ sf) {
  int c = blockIdx.x, b = blockIdx.y;
  __shared__ __align__(16) float pl[HH*WW];
  const f4* p4 = (const f4*)(feat + ((size_t)(b*CCH + c)) * (size_t)(HH*WW));
  f4* s4 = (f4*)pl;
  #pragma unroll
  for (int r = 0; r < 4; ++r) s4[threadIdx.x + r*256] = p4[threadIdx.x + r*256];
  __syncthreads();
  int j = threadIdx.x;
  if (j < JJ) {
    float gx = kp[((size_t)b*JJ + j)*2 + 0];
    float gy = kp[((size_t)b*JJ + j)*2 + 1];
    float ix = (gx + 1.0f) * 0.5f * (float)(WW - 1);
    float iy = (gy + 1.0f) * 0.5f * (float)(HH - 1);
    sf[((size_t)(b*CCH + c))*JJ + j] = bilin(pl, ix, iy);
  }
}

// Partial hidden GEMM. grid (8 jq, 2 ch, 32 b); JT=16, K-chunk=512.
// part[ch][b][m][o][j] = sum_{c in chunk} wt[m][c][o]*seed[b][c][j]
__global__ __launch_bounds__(256) void k_mlp(const float* __restrict__ sf,
                                             const float* __restrict__ wt,
                                             float* __restrict__ part) {
  int jq = blockIdx.x, ch = blockIdx.y, b = blockIdx.z;
  int j0 = jq * 16;
  __shared__ __align__(16) float sW[2][64][HID];   // 64 KB
  __shared__ __align__(16) float sS[64][16];       // 4 KB
  int t = threadIdx.x;
  int ocol = t & 31, jrow = t >> 5;
  int o0 = ocol * 4, jl0 = jrow * 2;
  f4 a00 = 0.0f, a01 = 0.0f, a10 = 0.0f, a11 = 0.0f;

  for (int kt = 0; kt < 8; ++kt) {
    int c0 = ch * 512 + kt * 64;
    // stage S tile: 64c x 16j = 256 f4 (1 per thread)
    {
      int cc = t >> 2, q = t & 3;
      *(f4*)&sS[cc][q*4] = *(const f4*)&sf[((size_t)(b*CCH + c0 + cc))*JJ + j0 + q*4];
    }
    // stage W tiles: 2m x 64c x 128o = 4096 f4 (16 per thread), contiguous in o
    #pragma unroll
    for (int r = 0; r < 16; ++r) {
      int idx = r * 256 + t;
      int m = idx >> 11;
      int rem = idx & 2047;
      int cc = rem >> 5, oq = rem & 31;
      *(f4*)&sW[m][cc][oq*4] =
          *(const f4*)&wt[(size_t)m*(CCH*HID) + (size_t)(c0 + cc)*HID + oq*4];
    }
    __syncthreads();
    #pragma unroll 8
    for (int cc = 0; cc < 64; ++cc) {
      f4 w0 = *(const f4*)&sW[0][cc][o0];
      f4 w1 = *(const f4*)&sW[1][cc][o0];
      float s0 = sS[cc][jl0], s1 = sS[cc][jl0 + 1];
      a00 += w0 * s0; a01 += w0 * s1;
      a10 += w1 * s0; a11 += w1 * s1;
    }
    __syncthreads();
  }
  size_t half = (size_t)BB * 2 * HID * JJ;
  #pragma unroll
  for (int oi = 0; oi < 4; ++oi) {
    size_t base0 = (size_t)ch*half + (((size_t)(b*2 + 0))*HID + o0 + oi)*JJ + j0 + jl0;
    size_t base1 = (size_t)ch*half + (((size_t)(b*2 + 1))*HID + o0 + oi)*JJ + j0 + jl0;
    f2 v0; v0[0] = a00[oi]; v0[1] = a01[oi];
    f2 v1; v1[0] = a10[oi]; v1[1] = a11[oi];
    *(f2*)&part[base0] = v0;
    *(f2*)&part[base1] = v1;
  }
}

// Reduce partials + bias + relu, layer2, softmax, new grid coords.
__global__ __launch_bounds__(256) void k_head(const float* __restrict__ part,
                                              const float* __restrict__ kp,
                                              const float* __restrict__ b_off1,
                                              const float* __restrict__ w_off2,
                                              const float* __restrict__ b_off2,
                                              const float* __restrict__ b_att1,
                                              const float* __restrict__ w_att2,
                                              const float* __restrict__ b_att2,
                                              float* __restrict__ grids,
                                              float* __restrict__ attw) {
  int jq = blockIdx.x, b = blockIdx.y;
  int j0 = jq * 32;
  __shared__ float sH[2][HID][33];
  __shared__ float sO[32][13];
  size_t half = (size_t)BB * 2 * HID * JJ;
  for (int idx = threadIdx.x; idx < 2*HID*32; idx += 256) {
    int m = idx >> 12;
    int rem = idx & 4095;
    int o = rem >> 5, jl = rem & 31;
    size_t base = (((size_t)(b*2 + m))*HID + o)*JJ + j0 + jl;
    float v = part[base] + part[half + base];
    v += (m ? b_att1 : b_off1)[o];
    sH[m][o][jl] = fmaxf(v, 0.0f);
  }
  __syncthreads();
  for (int idx = threadIdx.x; idx < 12*32; idx += 256) {
    int jl = idx / 12, q = idx % 12;
    int m = (q < 8) ? 0 : 1;
    int p = m ? (q - 8) : q;
    const float* w2 = m ? w_att2 : w_off2;
    float sum = (m ? b_att2 : b_off2)[p];
    for (int o = 0; o < HID; ++o) sum += w2[p*HID + o] * sH[m][o][jl];
    sO[jl][q] = sum;
  }
  __syncthreads();
  if (threadIdx.x < 32) {
    int jl = threadIdx.x, j = j0 + jl;
    float gx = kp[((size_t)b*JJ + j)*2 + 0];
    float gy = kp[((size_t)b*JJ + j)*2 + 1];
    const float sc = 2.0f / 63.0f;
    float a[NP];
    #pragma unroll
    for (int n = 0; n < NP; ++n) {
      grids[(((size_t)b*JJ + j)*NP + n)*2 + 0] = gx + sO[jl][2*n + 0]*sc;
      grids[(((size_t)b*JJ + j)*NP + n)*2 + 1] = gy + sO[jl][2*n + 1]*sc;
      a[n] = sO[jl][8 + n];
    }
    float mx = fmaxf(fmaxf(a[0], a[1]), fmaxf(a[2], a[3]));
    float e[NP], s = 0.0f;
    #pragma unroll
    for (int n = 0; n < NP; ++n) { e[n] = expf(a[n] - mx); s += e[n]; }
    float inv = 1.0f / s;
    #pragma unroll
    for (int n = 0; n < NP; ++n) attw[((size_t)b*JJ + j)*NP + n] = e[n]*inv;
  }
}

// fusedT[b][c][j] = sum_n attw[b][j][n] * bilinear(features[b,c], grids[b][j][n])
__global__ __launch_bounds__(256) void k_fuse(const float* __restrict__ feat,
                                              const float* __restrict__ grids,
                                              const float* __restrict__ attw,
                                              float* __restrict__ fusedT) {
  int c = blockIdx.x, b = blockIdx.y;
  __shared__ __align__(16) float pl[HH*WW];
  __shared__ float sG[JJ*NP*2];
  __shared__ float sA[JJ*NP];
  const f4* p4 = (const f4*)(feat + ((size_t)(b*CCH + c)) * (size_t)(HH*WW));
  f4* s4 = (f4*)pl;
  #pragma unroll
  for (int r = 0; r < 4; ++r) s4[threadIdx.x + r*256] = p4[threadIdx.x + r*256];
  const float* gb = grids + (size_t)b*JJ*NP*2;
  const float* ab = attw  + (size_t)b*JJ*NP;
  for (int i = threadIdx.x; i < JJ*NP*2; i += 256) sG[i] = gb[i];
  for (int i = threadIdx.x; i < JJ*NP;   i += 256) sA[i] = ab[i];
  __syncthreads();
  int j = threadIdx.x;
  if (j < JJ) {
    float acc = 0.0f;
    #pragma unroll
    for (int n = 0; n < NP; ++n) {
      float gx = sG[(j*NP + n)*2 + 0];
      float gy = sG[(j*NP + n)*2 + 1];
      float ix = (gx + 1.0f) * 0.5f * (float)(WW - 1);
      float iy = (gy + 1.0f) * 0.5f * (float)(HH - 1);
      acc += sA[j*NP + n] * bilin(pl, ix, iy);
    }
    fusedT[((size_t)(b*CCH + c))*JJ + j] = acc;
  }
}

// out[b][j][c] = fusedT[b][c][j]
__global__ __launch_bounds__(256) void k_tr(const float* __restrict__ fusedT,
                                            float* __restrict__ out) {
  int b = blockIdx.z;
  int c0 = blockIdx.x * 32, j0 = blockIdx.y * 32;
  __shared__ float tl[32][33];
  int tx = threadIdx.x & 31, ty = threadIdx.x >> 5;
  #pragma unroll
  for (int r = 0; r < 4; ++r) {
    int cc = ty + r*8;
    tl[cc][tx] = fusedT[((size_t)(b*CCH + c0 + cc))*JJ + j0 + tx];
  }
  __syncthreads();
  #pragma unroll
  for (int r = 0; r < 4; ++r) {
    int jj = ty + r*8;
    out[((size_t)(b*JJ + j0 + jj))*CCH + c0 + tx] = tl[tx][jj];
  }
}

extern "C" void kernel_launch(void* const* d_in, const int* in_sizes, int n_in,
                              void* d_out, int out_size, void* d_ws, size_t ws_size,
                              hipStream_t stream) {
  const float* feat   = (const float*)d_in[0];
  const float* kp     = (const float*)d_in[1];
  const float* w_off1 = (const float*)d_in[2];
  const float* b_off1 = (const float*)d_in[3];
  const float* w_off2 = (const float*)d_in[4];
  const float* b_off2 = (const float*)d_in[5];
  const float* w_att1 = (const float*)d_in[6];
  const float* b_att1 = (const float*)d_in[7];
  const float* w_att2 = (const float*)d_in[8];
  const float* b_att2 = (const float*)d_in[9];
  float* out = (float*)d_out;

  // workspace (floats), 26.4 MB total (same footprint as proven R2 layout):
  //   wt    : 0       .. 262144   (transposed W1, both MLPs)
  //   sf    : 262144  .. 4456448  (seed, later fusedT)
  //   part  : 4456448 .. 6553600  (2 c-halves of hidden partials)
  //   grids : 6553600 .. 6586368
  //   attw  : 6586368 .. 6602752
  float* ws    = (float*)d_ws;
  float* wt    = ws;
  float* sf    = ws + (size_t)262144;
  float* part  = ws + (size_t)4456448;
  float* grids = ws + (size_t)6553600;
  float* attwb = ws + (size_t)6586368;

  k_wtr <<<dim3(CCH/32, HID/32, 2), 256, 0, stream>>>(w_off1, w_att1, wt);
  k_seed<<<dim3(CCH, BB), 256, 0, stream>>>(feat, kp, sf);
  k_mlp <<<dim3(8, 2, BB), 256, 0, stream>>>(sf, wt, part);
  k_head<<<dim3(4, BB), 256, 0, stream>>>(part, kp, b_off1, w_off2, b_off2,
                                          b_att1, w_att2, b_att2, grids, attwb);
  k_fuse<<<dim3(CCH, BB), 256, 0, stream>>>(feat, grids, attwb, sf /*fusedT*/);
  k_tr  <<<dim3(CCH/32, JJ/32, BB), 256, 0, stream>>>(sf, out);
}

// Round 6
// 245.668 us; speedup vs baseline: 1.4286x; 1.1749x over previous
//
#include <hip/hip_runtime.h>
#include <math.h>

#define BB  32
#define CCH 1024
#define HH  64
#define WW  64
#define JJ  128
#define NP  4
#define HID 128

typedef float f4 __attribute__((ext_vector_type(4)));
typedef __attribute__((ext_vector_type(8))) short bf8_t;   // 8 bf16 (4 VGPRs)
typedef __attribute__((ext_vector_type(4))) float f32x4;
typedef __attribute__((ext_vector_type(4))) unsigned short us4;

__device__ __forceinline__ unsigned short f2bf(float x) {
  union { float f; unsigned int u; } v; v.f = x;
  unsigned int u = v.u;
  return (unsigned short)((u + 0x7FFFu + ((u >> 16) & 1u)) >> 16);
}

__device__ __forceinline__ float bilin(const float* pl, float ix, float iy) {
  float x0f = floorf(ix), y0f = floorf(iy);
  float wx1 = ix - x0f, wx0 = 1.0f - wx1;
  float wy1 = iy - y0f, wy0 = 1.0f - wy1;
  int x0 = (int)x0f, y0 = (int)y0f;
  int x1 = x0 + 1, y1 = y0 + 1;
  float v = 0.0f;
  if (y0 >= 0 && y0 < HH) {
    if (x0 >= 0 && x0 < WW) v += pl[y0*WW + x0] * (wx0*wy0);
    if (x1 >= 0 && x1 < WW) v += pl[y0*WW + x1] * (wx1*wy0);
  }
  if (y1 >= 0 && y1 < HH) {
    if (x0 >= 0 && x0 < WW) v += pl[y1*WW + x0] * (wx0*wy1);
    if (x1 >= 0 && x1 < WW) v += pl[y1*WW + x1] * (wx1*wy1);
  }
  return v;
}

// Cast W1 (both MLPs) f32 [o][c] -> bf16 [m][o][c]
__global__ __launch_bounds__(256) void k_prep(const float* __restrict__ w_off1,
                                              const float* __restrict__ w_att1,
                                              unsigned short* __restrict__ Wb) {
  int o = blockIdx.x, m = blockIdx.y;
  const float* src = (m ? w_att1 : w_off1) + (size_t)o * CCH;
  unsigned short* dst = Wb + ((size_t)m * HID + o) * CCH;
  int t = threadIdx.x;
  f4 v = *(const f4*)&src[t * 4];
  us4 u; u[0] = f2bf(v[0]); u[1] = f2bf(v[1]); u[2] = f2bf(v[2]); u[3] = f2bf(v[3]);
  *(us4*)&dst[t * 4] = u;
}

// seedB[b][c][j] = bf16(bilinear(features[b,c,:,:], keypoint[b,j]))
__global__ __launch_bounds__(256) void k_seed(const float* __restrict__ feat,
                                              const float* __restrict__ kp,
                                              unsigned short* __restrict__ seedB) {
  int c = blockIdx.x, b = blockIdx.y;
  __shared__ __align__(16) float pl[HH*WW];
  const f4* p4 = (const f4*)(feat + ((size_t)(b*CCH + c)) * (size_t)(HH*WW));
  f4* s4 = (f4*)pl;
  #pragma unroll
  for (int r = 0; r < 4; ++r) s4[threadIdx.x + r*256] = p4[threadIdx.x + r*256];
  __syncthreads();
  int j = threadIdx.x;
  if (j < JJ) {
    float gx = kp[((size_t)b*JJ + j)*2 + 0];
    float gy = kp[((size_t)b*JJ + j)*2 + 1];
    float ix = (gx + 1.0f) * 0.5f * (float)(WW - 1);
    float iy = (gy + 1.0f) * 0.5f * (float)(HH - 1);
    seedB[((size_t)(b*CCH + c))*JJ + j] = f2bf(bilin(pl, ix, iy));
  }
}

// Transpose: seedB bf16 [b][c][j] -> seedT bf16 [b][j][c]
__global__ __launch_bounds__(256) void k_str(const unsigned short* __restrict__ seedB,
                                             unsigned short* __restrict__ seedT) {
  int c0 = blockIdx.x * 32, j0 = blockIdx.y * 32, b = blockIdx.z;
  __shared__ unsigned short tl[32][34];
  int tx = threadIdx.x & 31, ty = threadIdx.x >> 5;
  #pragma unroll
  for (int r = 0; r < 4; ++r)
    tl[ty + r*8][tx] = seedB[((size_t)(b*CCH + c0 + ty + r*8))*JJ + j0 + tx];
  __syncthreads();
  #pragma unroll
  for (int r = 0; r < 4; ++r) {
    int jr = ty + r*8;
    seedT[((size_t)b*JJ + j0 + jr)*CCH + c0 + tx] = tl[tx][jr];
  }
}

// MFMA hidden GEMM: hidden[b][m][j][o] = relu(sum_c W[m][o][c]*seedT[b][j][c] + bias)
// M=j(128), N=o(128), K=1024. grid (2 m, 32 b), 4 waves.
__global__ __launch_bounds__(256) void k_mlp2(const unsigned short* __restrict__ seedT,
                                              const unsigned short* __restrict__ Wb,
                                              const float* __restrict__ b_off1,
                                              const float* __restrict__ b_att1,
                                              float* __restrict__ hidden) {
  int m = blockIdx.x, b = blockIdx.y;
  __shared__ __align__(16) unsigned short sA[128][72];  // [j][k], +8 pad
  __shared__ __align__(16) unsigned short sB[128][72];  // [o][k], +8 pad
  int t = threadIdx.x;
  int w = t >> 6, l = t & 63;
  int lr = l & 15, lg = l >> 4;
  f32x4 acc[2][8];
  #pragma unroll
  for (int jt = 0; jt < 2; ++jt)
    #pragma unroll
    for (int ot = 0; ot < 8; ++ot) acc[jt][ot] = (f32x4)0.0f;

  const unsigned short* At = seedT + (size_t)b * JJ * CCH;   // [j][c]
  const unsigned short* Bt = Wb + (size_t)m * HID * CCH;     // [o][c]

  for (int kc = 0; kc < 16; ++kc) {
    int k0 = kc * 64;
    // stage A,B tiles (128 rows x 64 k): 1024 x 16B chunks each, 4 per thread
    #pragma unroll
    for (int q = 0; q < 4; ++q) {
      int idx = q * 256 + t;
      int r = idx >> 3, s = idx & 7;
      *(bf8_t*)&sA[r][s*8] = *(const bf8_t*)&At[(size_t)r*CCH + k0 + s*8];
      *(bf8_t*)&sB[r][s*8] = *(const bf8_t*)&Bt[(size_t)r*CCH + k0 + s*8];
    }
    __syncthreads();
    #pragma unroll
    for (int ks = 0; ks < 2; ++ks) {
      int koff = ks*32 + lg*8;
      bf8_t a0 = *(const bf8_t*)&sA[w*32 + lr][koff];
      bf8_t a1 = *(const bf8_t*)&sA[w*32 + 16 + lr][koff];
      #pragma unroll
      for (int ot = 0; ot < 8; ++ot) {
        bf8_t bb = *(const bf8_t*)&sB[ot*16 + lr][koff];
        acc[0][ot] = __builtin_amdgcn_mfma_f32_16x16x32_bf16(a0, bb, acc[0][ot], 0, 0, 0);
        acc[1][ot] = __builtin_amdgcn_mfma_f32_16x16x32_bf16(a1, bb, acc[1][ot], 0, 0, 0);
      }
    }
    __syncthreads();
  }

  const float* bias = m ? b_att1 : b_off1;
  float* Hb = hidden + ((size_t)b * 2 + m) * JJ * HID;
  #pragma unroll
  for (int jt = 0; jt < 2; ++jt) {
    #pragma unroll
    for (int ot = 0; ot < 8; ++ot) {
      int o = ot*16 + lr;
      float bo = bias[o];
      #pragma unroll
      for (int r = 0; r < 4; ++r) {
        int j = w*32 + jt*16 + lg*4 + r;
        Hb[(size_t)j*HID + o] = fmaxf(acc[jt][ot][r] + bo, 0.0f);
      }
    }
  }
}

// layer2 + softmax + grid coords from hidden[b][m][j][o]. grid (4 jq, 32 b).
__global__ __launch_bounds__(256) void k_head2(const float* __restrict__ hidden,
                                               const float* __restrict__ kp,
                                               const float* __restrict__ w_off2,
                                               const float* __restrict__ b_off2,
                                               const float* __restrict__ w_att2,
                                               const float* __restrict__ b_att2,
                                               float* __restrict__ grids,
                                               float* __restrict__ attw) {
  int jq = blockIdx.x, b = blockIdx.y;
  int j0 = jq * 32;
  __shared__ __align__(16) float sH[2][32][132];
  __shared__ float sO[32][13];
  int t = threadIdx.x;
  for (int idx = t; idx < 2048; idx += 256) {      // 2048 f4 = 2*32*128 floats
    int m = idx >> 10, rem = idx & 1023;
    int jl = rem >> 5, oq = rem & 31;
    *(f4*)&sH[m][jl][oq*4] =
        *(const f4*)&hidden[(((size_t)b*2 + m)*JJ + j0 + jl)*HID + oq*4];
  }
  __syncthreads();
  for (int idx = t; idx < 12*32; idx += 256) {
    int jl = idx / 12, q = idx % 12;
    int m = (q < 8) ? 0 : 1;
    int p = m ? (q - 8) : q;
    const float* w2 = m ? w_att2 : w_off2;
    float sum = (m ? b_att2 : b_off2)[p];
    for (int o = 0; o < HID; ++o) sum += w2[p*HID + o] * sH[m][jl][o];
    sO[jl][q] = sum;
  }
  __syncthreads();
  if (t < 32) {
    int jl = t, j = j0 + jl;
    float gx = kp[((size_t)b*JJ + j)*2 + 0];
    float gy = kp[((size_t)b*JJ + j)*2 + 1];
    const float sc = 2.0f / 63.0f;
    float a[NP];
    #pragma unroll
    for (int n = 0; n < NP; ++n) {
      grids[(((size_t)b*JJ + j)*NP + n)*2 + 0] = gx + sO[jl][2*n + 0]*sc;
      grids[(((size_t)b*JJ + j)*NP + n)*2 + 1] = gy + sO[jl][2*n + 1]*sc;
      a[n] = sO[jl][8 + n];
    }
    float mx = fmaxf(fmaxf(a[0], a[1]), fmaxf(a[2], a[3]));
    float e[NP], s = 0.0f;
    #pragma unroll
    for (int n = 0; n < NP; ++n) { e[n] = expf(a[n] - mx); s += e[n]; }
    float inv = 1.0f / s;
    #pragma unroll
    for (int n = 0; n < NP; ++n) attw[((size_t)b*JJ + j)*NP + n] = e[n]*inv;
  }
}

// Fused gather + attention blend, direct transposed output.
// Block: 16 channels of one batch; loops planes with reg-prefetch double buffer.
__global__ __launch_bounds__(256) void k_fuse2(const float* __restrict__ feat,
                                               const float* __restrict__ grids,
                                               const float* __restrict__ attw,
                                               float* __restrict__ out) {
  int c0 = blockIdx.x * 16, b = blockIdx.y;
  __shared__ __align__(16) float plane[2][HH*WW];   // 32 KB
  __shared__ float sT[JJ][17];
  __shared__ float sG[JJ*NP*2];
  __shared__ float sAw[JJ*NP];
  int t = threadIdx.x;
  const f4* gb = (const f4*)(grids + (size_t)b*JJ*NP*2);
  const f4* ab = (const f4*)(attw  + (size_t)b*JJ*NP);
  ((f4*)sG)[t] = gb[t];
  if (t < 128) ((f4*)sAw)[t] = ab[t];

  const float* base = feat + ((size_t)(b*CCH + c0)) * (size_t)(HH*WW);
  f4 r[4];
  {
    const f4* p0 = (const f4*)base;
    #pragma unroll
    for (int q = 0; q < 4; ++q) r[q] = p0[t + q*256];
    f4* d = (f4*)plane[0];
    #pragma unroll
    for (int q = 0; q < 4; ++q) d[t + q*256] = r[q];
  }
  __syncthreads();

  for (int i = 0; i < 16; ++i) {
    int cur = i & 1;
    if (i < 15) {
      const f4* pn = (const f4*)(base + (size_t)(i + 1) * (HH*WW));
      #pragma unroll
      for (int q = 0; q < 4; ++q) r[q] = pn[t + q*256];
    }
    if (t < JJ) {
      float acc = 0.0f;
      #pragma unroll
      for (int n = 0; n < NP; ++n) {
        float gx = sG[(t*NP + n)*2 + 0];
        float gy = sG[(t*NP + n)*2 + 1];
        float ix = (gx + 1.0f) * 0.5f * (float)(WW - 1);
        float iy = (gy + 1.0f) * 0.5f * (float)(HH - 1);
        acc += sAw[t*NP + n] * bilin(plane[cur], ix, iy);
      }
      sT[t][i] = acc;
    }
    __syncthreads();
    if (i < 15) {
      f4* d = (f4*)plane[cur ^ 1];
      #pragma unroll
      for (int q = 0; q < 4; ++q) d[t + q*256] = r[q];
    }
    __syncthreads();
  }

  if (t < JJ) {
    f4* dst = (f4*)&out[((size_t)b*JJ + t)*CCH + c0];
    #pragma unroll
    for (int q = 0; q < 4; ++q) {
      f4 v;
      v[0] = sT[t][q*4 + 0]; v[1] = sT[t][q*4 + 1];
      v[2] = sT[t][q*4 + 2]; v[3] = sT[t][q*4 + 3];
      dst[q] = v;
    }
  }
}

extern "C" void kernel_launch(void* const* d_in, const int* in_sizes, int n_in,
                              void* d_out, int out_size, void* d_ws, size_t ws_size,
                              hipStream_t stream) {
  const float* feat   = (const float*)d_in[0];
  const float* kp     = (const float*)d_in[1];
  const float* w_off1 = (const float*)d_in[2];
  const float* b_off1 = (const float*)d_in[3];
  const float* w_off2 = (const float*)d_in[4];
  const float* b_off2 = (const float*)d_in[5];
  const float* w_att1 = (const float*)d_in[6];
  const float* b_att1 = (const float*)d_in[7];
  const float* w_att2 = (const float*)d_in[8];
  const float* b_att2 = (const float*)d_in[9];
  float* out = (float*)d_out;

  // workspace (float offsets), 21.7 MB total:
  //   grids        : 0        .. 32768     (32*128*4*2 f32)
  //   attw         : 32768    .. 49152     (32*128*4 f32)
  //   Wb  (ushort) : 49152    .. 180224    (2*128*1024 bf16 = 524288 B = 131072 slots)
  //   seedB(ushort): 180224   .. 2277376   (32*1024*128 bf16, [b][c][j])
  //   seedT(ushort): 2277376  .. 4374528   (32*128*1024 bf16, [b][j][c])
  //   hidden f32   : 4374528  .. 5423104   (32*2*128*128)
  float* ws = (float*)d_ws;
  float*          grids = ws;
  float*          attwb = ws + (size_t)32768;
  unsigned short* Wb    = (unsigned short*)(ws + (size_t)49152);
  unsigned short* seedB = (unsigned short*)(ws + (size_t)180224);
  unsigned short* seedT = (unsigned short*)(ws + (size_t)2277376);
  float*          hid   = ws + (size_t)4374528;

  k_prep <<<dim3(HID, 2), 256, 0, stream>>>(w_off1, w_att1, Wb);
  k_seed <<<dim3(CCH, BB), 256, 0, stream>>>(feat, kp, seedB);
  k_str  <<<dim3(CCH/32, JJ/32, BB), 256, 0, stream>>>(seedB, seedT);
  k_mlp2 <<<dim3(2, BB), 256, 0, stream>>>(seedT, Wb, b_off1, b_att1, hid);
  k_head2<<<dim3(4, BB), 256, 0, stream>>>(hid, kp, w_off2, b_off2, w_att2, b_att2,
                                           grids, attwb);
  k_fuse2<<<dim3(CCH/16, BB), 256, 0, stream>>>(feat, grids, attwb, out);
}